// Round 1
// baseline (94.281 us; speedup 1.0000x reference)
//
#include <hip/hip_runtime.h>

// Problem constants
#define BB 4
#define CC 32
#define HH 64
#define WW 64
#define KK 64
#define PIX (HH * WW)      // 4096
#define NBC (BB * CC)      // 128 planes

// ---------------------------------------------------------------------------
// Sparse restructure. Gaussian RFs are thresholded at 0.05 with sigma in
// [4,7): support radius^2 < 2*49*ln(20) ~ 294 -> <= ~920 of 4096 pixels per
// kernel (avg ~580). ~86% of rf entries are exactly zero. We build compact
// lists once per launch and only touch nonzeros:
//   prep:   per-k pixel lists (pixel-ordered, coalesced) + per-pixel (rf,k)
//           slot lists (slot-major, coalesced across lanes)
//   phase1: inv_k(bc) = 1/(1+sum exp(u*rf)) over the ~580-entry support
//   phase2: h[p] = sum over the ~9-25 active k's; 2x2 max-pool
// Numerics identical to the previously verified no-max-subtraction form
// (absmax was 0.0; only summation order changes).
// ---------------------------------------------------------------------------

// workspace layout (float offsets; all 4B/8B aligned)
#define OFF_INV    0        // 128*64 floats             (32 KB)
#define OFF_KCNT   8192     // 64 ints
#define OFF_PCNT   8320     // 4096 ints
#define OFF_PLIST  12416    // float2[64*1024]  (val, pixel-as-int-bits)
#define OFF_PXLIST 143488   // float2[64*4096]  (val, k-as-int-bits), slot-major

// ---------------------------------------------------------------------------
// Prep: blocks 0..63 build per-k lists (4 waves, two-pass ballot compaction,
// globally pixel-ordered). Blocks 64..79: thread-per-pixel builds slot lists.
// ---------------------------------------------------------------------------
__global__ __launch_bounds__(256) void rf_prep(
        const float* __restrict__ rfs, float* __restrict__ ws) {
    int*    kcnt   = (int*)(ws + OFF_KCNT);
    int*    pcnt   = (int*)(ws + OFF_PCNT);
    float2* plist  = (float2*)(ws + OFF_PLIST);
    float2* pxlist = (float2*)(ws + OFF_PXLIST);
    const int bid = blockIdx.x;

    if (bid < KK) {
        const int k = bid;
        const int t = threadIdx.x, w = t >> 6, l = t & 63;
        __shared__ int scnt[4];
        const float* rk = rfs + (size_t)k * PIX;
        unsigned long long masks[16];
        float vals[16];
        int cnt = 0;
        #pragma unroll
        for (int i = 0; i < 16; ++i) {
            const int p = (w * 16 + i) * 64 + l;
            const float v = rk[p];
            vals[i] = v;
            const unsigned long long m = __ballot(v > 0.f);
            masks[i] = m;
            cnt += __popcll(m);
        }
        if (l == 0) scnt[w] = cnt;
        __syncthreads();
        int base = 0;
        #pragma unroll
        for (int j = 0; j < 4; ++j) base += (j < w) ? scnt[j] : 0;
        if (w == 3 && l == 0) kcnt[k] = base + cnt;
        const unsigned long long lmask = (1ull << l) - 1ull;
        #pragma unroll
        for (int i = 0; i < 16; ++i) {
            const int p = (w * 16 + i) * 64 + l;
            const unsigned long long m = masks[i];
            if (vals[i] > 0.f) {
                const int idx = base + (int)__popcll(m & lmask);
                plist[k * 1024 + idx] = make_float2(vals[i], __int_as_float(p));
            }
            base += (int)__popcll(m);
        }
    } else {
        // per-pixel slot lists
        const int p = (bid - KK) * 256 + threadIdx.x;   // 16 blocks * 256 = 4096
        int c = 0;
        for (int k = 0; k < KK; ++k) {
            const float v = rfs[(size_t)k * PIX + p];
            if (v > 0.f) {
                pxlist[c * PIX + p] = make_float2(v, __int_as_float(k));
                ++c;
            }
        }
        pcnt[p] = c;
    }
}

// ---------------------------------------------------------------------------
// Phase 1: one WAVE per (bc,k). Scans only the support list (~9 iters avg).
// List is pixel-ordered -> u gathers are mostly-coalesced L1/L2 hits.
// No LDS, no barriers.
// ---------------------------------------------------------------------------
__global__ __launch_bounds__(256) void rf_phase1(
        const float* __restrict__ u, float* __restrict__ ws) {
    float*        inv   = ws + OFF_INV;
    const int*    kcnt  = (const int*)(ws + OFF_KCNT);
    const float2* plist = (const float2*)(ws + OFF_PLIST);

    const int bc = blockIdx.x >> 4;
    const int k  = (blockIdx.x & 15) * 4 + (threadIdx.x >> 6);
    const int l  = threadIdx.x & 63;

    const int n = kcnt[k];                       // wave-uniform
    const float*  up = u + (size_t)bc * PIX;
    const float2* lp = plist + k * 1024;

    float s = 0.f;
    for (int e = l; e < n; e += 64) {
        const float2 ev = lp[e];
        const float uu  = up[__float_as_int(ev.y)];
        s += __expf(uu * ev.x);
    }
    #pragma unroll
    for (int off = 32; off > 0; off >>= 1)
        s += __shfl_xor(s, off, 64);
    if (l == 0) inv[bc * KK + k] = 1.f / (1.f + s);
}

// ---------------------------------------------------------------------------
// Phase 2: one WAVE per (bc, row-pair). Thread l owns pixels (2rp,l),(2rp+1,l).
// Ragged per-lane loop over that pixel's active RFs (avg ~9, wave-max ~25).
// inv[64] staged in LDS, gathered per entry (random over 64 floats ~ 2-way
// bank alias, free). 2x2 pool: vertical in-register, horizontal shfl_xor(1).
// ---------------------------------------------------------------------------
__global__ __launch_bounds__(256) void rf_phase2(
        const float* __restrict__ u, const float* __restrict__ ws,
        float* __restrict__ out) {
    const float*  inv    = ws + OFF_INV;
    const int*    pcnt   = (const int*)(ws + OFF_PCNT);
    const float2* pxlist = (const float2*)(ws + OFF_PXLIST);

    __shared__ float sld[KK];
    const int bc = blockIdx.x >> 3;
    const int t  = threadIdx.x;
    if (t < KK) sld[t] = inv[bc * KK + t];
    __syncthreads();

    const int rp = (blockIdx.x & 7) * 4 + (t >> 6);   // row pair 0..31
    const int l  = t & 63;
    const int p0 = rp * 128 + l;
    const int p1 = p0 + 64;

    const float u0 = u[(size_t)bc * PIX + p0];
    const float u1 = u[(size_t)bc * PIX + p1];
    const int   c0 = pcnt[p0];
    const int   c1 = pcnt[p1];

    float h0 = 0.f, h1 = 0.f;
    for (int s = 0; s < c0; ++s) {
        const float2 ev = pxlist[s * PIX + p0];
        h0 += __expf(u0 * ev.x) * sld[__float_as_int(ev.y)];
    }
    for (int s = 0; s < c1; ++s) {
        const float2 ev = pxlist[s * PIX + p1];
        h1 += __expf(u1 * ev.x) * sld[__float_as_int(ev.y)];
    }

    const float v = fmaxf(h0, h1);
    const float o = fmaxf(v, __shfl_xor(v, 1, 64));
    if ((l & 1) == 0)
        out[(size_t)bc * (HH / 2) * (WW / 2) + rp * 32 + (l >> 1)] = o;
}

extern "C" void kernel_launch(void* const* d_in, const int* in_sizes, int n_in,
                              void* d_out, int out_size, void* d_ws, size_t ws_size,
                              hipStream_t stream) {
    const float* u   = (const float*)d_in[0];
    const float* rfs = (const float*)d_in[1];
    float* out       = (float*)d_out;
    float* ws        = (float*)d_ws;

    rf_prep  <<<KK + PIX / 256, 256, 0, stream>>>(rfs, ws);
    rf_phase1<<<NBC * 16,       256, 0, stream>>>(u, ws);
    rf_phase2<<<NBC * 8,        256, 0, stream>>>(u, ws, out);
}

// Round 2
// 82.183 us; speedup vs baseline: 1.1472x; 1.1472x over previous
//
#include <hip/hip_runtime.h>

// Problem constants (match reference)
#define BB 4
#define CC 32
#define HH 64
#define WW 64
#define KK 64
#define PIX (HH * WW)      // 4096
#define NBC (BB * CC)      // 128 planes

#define LOG2E 1.4426950408889634f

// v_exp_f32 is natively exp2 -> with u pre-scaled by log2(e) we get
// exp(u*rf) in ONE transcendental, no hidden mul (what __expf emits).
static __device__ __forceinline__ float fexp2(float x) {
    return __builtin_amdgcn_exp2f(x);
}

// ---------------------------------------------------------------------------
// Dense structure (round-0 skeleton, which measured 73.3us / absmax 0), with
// per-element op count cut to the minimum:
//   phase1/element: mul, exp2, cmp, cndmask, add            (was +1 mul)
//   phase2/element: mul, exp2, cmp, cndmask(inv,0), fmac    (was +1 mul, +load)
// Numerics: same no-max-subtraction form as before (values bounded ~e^6,
// far inside f32 range); exp2(u*log2e*rf) == exp(u*rf) to ~1ulp.
// ---------------------------------------------------------------------------

// Phase 1: one WAVE per (bc,k). grid = NBC*16 blocks x 256 thr.
// u plane staged in LDS once per block, PRE-SCALED by log2e at stage time.
__global__ __launch_bounds__(256) void rf_phase1(
        const float* __restrict__ u,
        const float* __restrict__ rfs,
        float* __restrict__ inv) {
    const int bc = blockIdx.x >> 4;
    const int kg = blockIdx.x & 15;
    const int t  = threadIdx.x;
    const int w  = t >> 6;
    const int l  = t & 63;

    __shared__ float su[PIX];    // 16 KB
    {
        const float4* u4  = (const float4*)(u + (size_t)bc * PIX);
        float4*       su4 = (float4*)su;
        #pragma unroll
        for (int i = 0; i < 4; ++i) {
            float4 v = u4[t + 256 * i];
            v.x *= LOG2E; v.y *= LOG2E; v.z *= LOG2E; v.w *= LOG2E;
            su4[t + 256 * i] = v;
        }
    }
    __syncthreads();

    const int k = kg * 4 + w;
    const float4* r4  = (const float4*)(rfs + (size_t)k * PIX);
    const float4* su4 = (const float4*)su;

    float s = 0.f;
    #pragma unroll
    for (int i = 0; i < 16; ++i) {
        const float4 rv = r4[64 * i + l];
        const float4 uv = su4[64 * i + l];
        s += (rv.x > 0.f) ? fexp2(uv.x * rv.x) : 0.f;
        s += (rv.y > 0.f) ? fexp2(uv.y * rv.y) : 0.f;
        s += (rv.z > 0.f) ? fexp2(uv.z * rv.z) : 0.f;
        s += (rv.w > 0.f) ? fexp2(uv.w * rv.w) : 0.f;
    }
    #pragma unroll
    for (int off = 32; off > 0; off >>= 1)
        s += __shfl_xor(s, off, 64);

    if (l == 0) inv[bc * KK + k] = 1.f / (1.f + s);
}

// Phase 2: thread owns a 2x2 pixel quad (rows 2qr,2qr+1; cols 2qc,2qc+1).
// grid = NBC*4 blocks x 256 thr (strip = 16 rows). rf read as float2 per row
// (0.5 load-instr/element, 256B-contiguous per 32-lane group). u loaded once
// into registers, pre-scaled. inv staged in LDS (uniform broadcast reads).
// Pooling is entirely in-thread: the quad IS one pooling block -> no shuffles.
__global__ __launch_bounds__(256) void rf_phase2(
        const float* __restrict__ u,
        const float* __restrict__ rfs,
        const float* __restrict__ inv,
        float* __restrict__ out) {
    __shared__ float sld[KK];
    const int bc    = blockIdx.x >> 2;
    const int strip = blockIdx.x & 3;                 // rows [16*strip, +16)
    const int t     = threadIdx.x;
    if (t < KK) sld[t] = inv[bc * KK + t];
    __syncthreads();

    const int qr = t >> 5;                            // row-pair 0..7
    const int qc = t & 31;                            // col-pair 0..31
    const int row0 = strip * 16 + 2 * qr;
    const int p00  = row0 * 64 + 2 * qc;              // 8B-aligned
    const int p10  = p00 + 64;

    const float* ub = u + (size_t)bc * PIX;
    float2 ua = *(const float2*)(ub + p00);
    float2 uc = *(const float2*)(ub + p10);
    ua.x *= LOG2E; ua.y *= LOG2E; uc.x *= LOG2E; uc.y *= LOG2E;

    const float* rp0 = rfs + p00;
    const float* rp1 = rfs + p10;

    float h00 = 0.f, h01 = 0.f, h10 = 0.f, h11 = 0.f;
    #pragma unroll 4
    for (int k = 0; k < KK; ++k) {
        const float2 ra = *(const float2*)(rp0 + (size_t)k * PIX);
        const float2 rb = *(const float2*)(rp1 + (size_t)k * PIX);
        const float  fi = sld[k];
        h00 += ((ra.x > 0.f) ? fi : 0.f) * fexp2(ua.x * ra.x);
        h01 += ((ra.y > 0.f) ? fi : 0.f) * fexp2(ua.y * ra.y);
        h10 += ((rb.x > 0.f) ? fi : 0.f) * fexp2(uc.x * rb.x);
        h11 += ((rb.y > 0.f) ? fi : 0.f) * fexp2(uc.y * rb.y);
    }

    const float o = fmaxf(fmaxf(h00, h01), fmaxf(h10, h11));
    out[(size_t)bc * (HH / 2) * (WW / 2) + (strip * 8 + qr) * 32 + qc] = o;
}

extern "C" void kernel_launch(void* const* d_in, const int* in_sizes, int n_in,
                              void* d_out, int out_size, void* d_ws, size_t ws_size,
                              hipStream_t stream) {
    const float* u   = (const float*)d_in[0];
    const float* rfs = (const float*)d_in[1];
    float* out       = (float*)d_out;
    float* inv       = (float*)d_ws;       // 128*64 floats = 32 KB scratch

    rf_phase1<<<NBC * 16, 256, 0, stream>>>(u, rfs, inv);
    rf_phase2<<<NBC * 4,  256, 0, stream>>>(u, rfs, inv, out);
}

// Round 3
// 78.805 us; speedup vs baseline: 1.1964x; 1.0429x over previous
//
#include <hip/hip_runtime.h>

// Problem constants (match reference)
#define BB 4
#define CC 32
#define HH 64
#define WW 64
#define KK 64
#define PIX (HH * WW)      // 4096
#define NBC (BB * CC)      // 128 planes

#define LOG2E 1.4426950408889634f

// v_exp_f32 is natively exp2 -> with u pre-scaled by log2(e), exp(u*rf)
// is ONE transcendental (no hidden mul).
static __device__ __forceinline__ float fexp2(float x) {
    return __builtin_amdgcn_exp2f(x);
}

// ---------------------------------------------------------------------------
// Lesson from r1/r2: these kernels are latency-bound, not ALU-bound.
// Keep r0's occupancy (phase2: 4096 waves, 4/SIMD), halve the load-issue
// count via float2 rf reads, and keep the exp2 prescale (free).
// ---------------------------------------------------------------------------

// Phase 1: one WAVE per (bc,k). grid = NBC*16 = 2048 blocks x 256 thr
// (8192 waves = 8/SIMD). u plane staged in LDS once per block, pre-scaled.
__global__ __launch_bounds__(256) void rf_phase1(
        const float* __restrict__ u,
        const float* __restrict__ rfs,
        float* __restrict__ inv) {
    const int bc = blockIdx.x >> 4;
    const int kg = blockIdx.x & 15;
    const int t  = threadIdx.x;
    const int w  = t >> 6;
    const int l  = t & 63;

    __shared__ float su[PIX];    // 16 KB
    {
        const float4* u4  = (const float4*)(u + (size_t)bc * PIX);
        float4*       su4 = (float4*)su;
        #pragma unroll
        for (int i = 0; i < 4; ++i) {
            float4 v = u4[t + 256 * i];
            v.x *= LOG2E; v.y *= LOG2E; v.z *= LOG2E; v.w *= LOG2E;
            su4[t + 256 * i] = v;
        }
    }
    __syncthreads();

    const int k = kg * 4 + w;
    const float4* r4  = (const float4*)(rfs + (size_t)k * PIX);
    const float4* su4 = (const float4*)su;

    float s = 0.f;
    #pragma unroll
    for (int i = 0; i < 16; ++i) {
        const float4 rv = r4[64 * i + l];
        const float4 uv = su4[64 * i + l];
        s += (rv.x > 0.f) ? fexp2(uv.x * rv.x) : 0.f;
        s += (rv.y > 0.f) ? fexp2(uv.y * rv.y) : 0.f;
        s += (rv.z > 0.f) ? fexp2(uv.z * rv.z) : 0.f;
        s += (rv.w > 0.f) ? fexp2(uv.w * rv.w) : 0.f;
    }
    #pragma unroll
    for (int off = 32; off > 0; off >>= 1)
        s += __shfl_xor(s, off, 64);

    if (l == 0) inv[bc * KK + k] = 1.f / (1.f + s);
}

// Phase 2: grid = NBC*8 = 1024 blocks x 256 thr (4096 waves = 4/SIMD, same
// occupancy as the 73.3us r0 version). Each WAVE covers a row PAIR: lanes
// 0..31 -> row 2r cols as float2 pairs, lanes 32..63 -> row 2r+1. One
// global_load_dwordx2 per (k, thread): the wave's 64 lanes cover 512
// contiguous bytes (both rows adjacent in memory) -> half the load
// instructions of r0 at identical wave count and elements/thread.
// Pooling: horizontal fmax in-thread, vertical via shfl_xor(32).
__global__ __launch_bounds__(256) void rf_phase2(
        const float* __restrict__ u,
        const float* __restrict__ rfs,
        const float* __restrict__ inv,
        float* __restrict__ out) {
    __shared__ float sld[KK];
    const int bc    = blockIdx.x >> 3;
    const int strip = blockIdx.x & 7;                 // 8 rows per strip
    const int t     = threadIdx.x;
    if (t < KK) sld[t] = inv[bc * KK + t];
    __syncthreads();

    const int w    = t >> 6;                          // wave 0..3
    const int l    = t & 63;
    const int row  = strip * 8 + 2 * w + (l >> 5);    // lanes<32: even row
    const int col2 = l & 31;                          // column pair index
    const int p    = row * 64 + 2 * col2;             // 8B-aligned

    const float* ub = u + (size_t)bc * PIX;
    float2 uv = *(const float2*)(ub + p);
    uv.x *= LOG2E; uv.y *= LOG2E;

    const float* rp = rfs + p;

    float h0 = 0.f, h1 = 0.f;
    #pragma unroll 8
    for (int k = 0; k < KK; ++k) {
        const float2 rv = *(const float2*)(rp + (size_t)k * PIX);
        const float  fi = sld[k];
        h0 += ((rv.x > 0.f) ? fi : 0.f) * fexp2(uv.x * rv.x);
        h1 += ((rv.y > 0.f) ? fi : 0.f) * fexp2(uv.y * rv.y);
    }

    float v = fmaxf(h0, h1);                          // horizontal
    v = fmaxf(v, __shfl_xor(v, 32, 64));              // vertical (row pair)
    if (l < 32)
        out[(size_t)bc * (HH / 2) * (WW / 2) + (strip * 4 + w) * 32 + col2] = v;
}

extern "C" void kernel_launch(void* const* d_in, const int* in_sizes, int n_in,
                              void* d_out, int out_size, void* d_ws, size_t ws_size,
                              hipStream_t stream) {
    const float* u   = (const float*)d_in[0];
    const float* rfs = (const float*)d_in[1];
    float* out       = (float*)d_out;
    float* inv       = (float*)d_ws;       // 128*64 floats = 32 KB scratch

    rf_phase1<<<NBC * 16, 256, 0, stream>>>(u, rfs, inv);
    rf_phase2<<<NBC * 8,  256, 0, stream>>>(u, rfs, inv, out);
}

// Round 4
// 77.758 us; speedup vs baseline: 1.2125x; 1.0135x over previous
//
#include <hip/hip_runtime.h>

// Problem constants (match reference)
#define BB 4
#define CC 32
#define HH 64
#define WW 64
#define KK 64
#define PIX (HH * WW)      // 4096
#define NBC (BB * CC)      // 128 planes

#define LOG2E 1.4426950408889634f

// v_exp_f32 is natively exp2 -> with u pre-scaled by log2(e), exp(u*rf)
// is ONE transcendental.
static __device__ __forceinline__ float fexp2(float x) {
    return __builtin_amdgcn_exp2f(x);
}

// ---------------------------------------------------------------------------
// Evidence from r0/r2/r3 A/B: phase-2 time tracks (waves/SIMD) x (bytes in
// flight per thread); op-count changes were neutral. r0 = 4 waves/SIMD x
// 128 B/thread. This version: 8 waves/SIMD x 64 B/thread (same 32 KB/SIMD
// aggregate, double the latency hiding). 1 px/thread, 64 scalar k-loads,
// unroll 16, VGPR capped at 64 via __launch_bounds__(256,8).
// ---------------------------------------------------------------------------

// Phase 1: one WAVE per (bc,k). grid = NBC*16 = 2048 blocks x 256 thr
// (8 waves/SIMD at 4+ blocks/CU). u plane staged in LDS, pre-scaled.
// Unchanged from the r0-equivalent structure (measured fast).
__global__ __launch_bounds__(256) void rf_phase1(
        const float* __restrict__ u,
        const float* __restrict__ rfs,
        float* __restrict__ inv) {
    const int bc = blockIdx.x >> 4;
    const int kg = blockIdx.x & 15;
    const int t  = threadIdx.x;
    const int w  = t >> 6;
    const int l  = t & 63;

    __shared__ float su[PIX];    // 16 KB
    {
        const float4* u4  = (const float4*)(u + (size_t)bc * PIX);
        float4*       su4 = (float4*)su;
        #pragma unroll
        for (int i = 0; i < 4; ++i) {
            float4 v = u4[t + 256 * i];
            v.x *= LOG2E; v.y *= LOG2E; v.z *= LOG2E; v.w *= LOG2E;
            su4[t + 256 * i] = v;
        }
    }
    __syncthreads();

    const int k = kg * 4 + w;
    const float4* r4  = (const float4*)(rfs + (size_t)k * PIX);
    const float4* su4 = (const float4*)su;

    float s = 0.f;
    #pragma unroll
    for (int i = 0; i < 16; ++i) {
        const float4 rv = r4[64 * i + l];
        const float4 uv = su4[64 * i + l];
        s += (rv.x > 0.f) ? fexp2(uv.x * rv.x) : 0.f;
        s += (rv.y > 0.f) ? fexp2(uv.y * rv.y) : 0.f;
        s += (rv.z > 0.f) ? fexp2(uv.z * rv.z) : 0.f;
        s += (rv.w > 0.f) ? fexp2(uv.w * rv.w) : 0.f;
    }
    #pragma unroll
    for (int off = 32; off > 0; off >>= 1)
        s += __shfl_xor(s, off, 64);

    if (l == 0) inv[bc * KK + k] = 1.f / (1.f + s);
}

// Phase 2: grid = NBC*16 = 2048 blocks x 256 thr -> 8192 waves = 8/SIMD
// (launch_bounds(256,8) caps VGPR at 64 so this occupancy is real).
// Thread owns ONE pixel: wave w = row (strip*4 + w), lane l = col.
// 64 scalar rf loads stride PIX, unroll 16 -> 16 loads (64 B) in flight.
// inv[k] is wave-uniform -> scalar s_load broadcast (no LDS stage).
// Pooling: horizontal via shfl_xor(1); vertical across wave pairs via
// a 512 B LDS exchange (waves 1,3 publish; waves 0,2 combine and store).
__global__ __launch_bounds__(256, 8) void rf_phase2(
        const float* __restrict__ u,
        const float* __restrict__ rfs,
        const float* __restrict__ inv,
        float* __restrict__ out) {
    __shared__ float sv[2][64];
    const int bc    = blockIdx.x >> 4;
    const int strip = blockIdx.x & 15;                // 4 rows per strip
    const int t     = threadIdx.x;
    const int w     = t >> 6;                         // wave = row in strip
    const int l     = t & 63;                         // lane = col

    const int row = strip * 4 + w;
    const int p   = row * 64 + l;

    const float u0 = u[(size_t)bc * PIX + p] * LOG2E;
    const float* __restrict__ invp = inv + bc * KK;   // uniform -> s_load
    const float* __restrict__ rfp  = rfs + p;

    float h = 0.f;
    #pragma unroll 16
    for (int k = 0; k < KK; ++k) {
        const float r  = rfp[(size_t)k * PIX];
        const float fi = invp[k];
        h += ((r > 0.f) ? fi : 0.f) * fexp2(u0 * r);
    }

    // horizontal 2:1 pool within the row (valid at even lanes)
    const float hv = fmaxf(h, __shfl_xor(h, 1, 64));

    // vertical pool across wave pairs (0,1) and (2,3)
    if (w & 1) sv[w >> 1][l] = hv;
    __syncthreads();
    if (!(w & 1) && !(l & 1)) {
        const float o = fmaxf(hv, sv[w >> 1][l]);
        const int por = strip * 2 + (w >> 1);         // pooled row 0..31
        out[(size_t)bc * (HH / 2) * (WW / 2) + por * 32 + (l >> 1)] = o;
    }
}

extern "C" void kernel_launch(void* const* d_in, const int* in_sizes, int n_in,
                              void* d_out, int out_size, void* d_ws, size_t ws_size,
                              hipStream_t stream) {
    const float* u   = (const float*)d_in[0];
    const float* rfs = (const float*)d_in[1];
    float* out       = (float*)d_out;
    float* inv       = (float*)d_ws;       // 128*64 floats = 32 KB scratch

    rf_phase1<<<NBC * 16, 256, 0, stream>>>(u, rfs, inv);
    rf_phase2<<<NBC * 16, 256, 0, stream>>>(u, rfs, inv, out);
}